// Round 5
// baseline (566.920 us; speedup 1.0000x reference)
//
#include <hip/hip_runtime.h>
#include <hip/hip_bf16.h>

#define BB   128
#define TT   256
#define CC   384
#define HH   6
#define HSZ  64
#define DFF  1536
#define EPSV 1e-5f
#define RPB  8
#define NTOK (BB * TT)          // 32768
#define NQKV (3 * CC)           // 1152

typedef __attribute__((ext_vector_type(8))) short  short8;
typedef __attribute__((ext_vector_type(4))) float  f32x4;
typedef __hip_bfloat16 bf16;

// async 16B global -> LDS (lane-contiguous at wave-uniform base)
__device__ __forceinline__ void async_copy16(const bf16* g, bf16* l) {
    __builtin_amdgcn_global_load_lds(
        (const __attribute__((address_space(1))) void*)g,
        (__attribute__((address_space(3))) void*)l, 16, 0, 0);
}

// ---------------- block-wide reduction over 384 threads (6 waves) -------------
__device__ __forceinline__ void block_reduce2(float& a, float& b, float* red) {
    #pragma unroll
    for (int off = 32; off > 0; off >>= 1) {
        a += __shfl_down(a, off, 64);
        b += __shfl_down(b, off, 64);
    }
    const int lane = threadIdx.x & 63;
    const int wid  = threadIdx.x >> 6;
    if (lane == 0) { red[wid * 2] = a; red[wid * 2 + 1] = b; }
    __syncthreads();
    if (threadIdx.x == 0) {
        float sa = 0.f, sb = 0.f;
        #pragma unroll
        for (int w = 0; w < 6; ++w) { sa += red[w * 2]; sb += red[w * 2 + 1]; }
        red[12] = sa; red[13] = sb;
    }
    __syncthreads();
    a = red[12]; b = red[13];
}

// ---------------- LN -> bf16 --------------------------------------------------
__global__ __launch_bounds__(CC) void ln_bf16_kernel(
        const float* __restrict__ x, const float* __restrict__ g,
        const float* __restrict__ be, bf16* __restrict__ y) {
    __shared__ float red[16];
    const int tid = threadIdx.x;
    const long row0 = (long)blockIdx.x * RPB;
    const float gg = g[tid], bb = be[tid];
    for (int r = 0; r < RPB; ++r) {
        float v = x[(row0 + r) * CC + tid];
        float s = v, sq = v * v;
        block_reduce2(s, sq, red);
        float mu  = s  * (1.0f / CC);
        float var = sq * (1.0f / CC) - mu * mu;
        float rs  = rsqrtf(var + EPSV);
        y[(row0 + r) * CC + tid] = __float2bfloat16((v - mu) * rs * gg + bb);
        __syncthreads();
    }
}

// ---------------- weight packing ----------------------------------------------
__global__ __launch_bounds__(CC) void pack_qkv_w(
        const float* __restrict__ Wq, const float* __restrict__ Wk,
        const float* __restrict__ Wv, bf16* __restrict__ WcatT) {
    const int n = blockIdx.x, k = threadIdx.x;
    const float* src; int nn;
    if (n < CC)          { src = Wq; nn = n; }
    else if (n < 2 * CC) { src = Wk; nn = n - CC; }
    else                 { src = Wv; nn = n - 2 * CC; }
    const int h = nn >> 6, d = nn & 63;
    WcatT[(long)n * CC + k] = __float2bfloat16(src[((long)h * CC + k) * HSZ + d]);
}

__global__ __launch_bounds__(256) void transpose_to_bf16(
        const float* __restrict__ in, bf16* __restrict__ out, int R, int Cn) {
    __shared__ float t[32][33];
    const int tid = threadIdx.x;
    const int tx = tid & 31, ty = tid >> 5;
    const int c0 = blockIdx.x * 32, r0 = blockIdx.y * 32;
    #pragma unroll
    for (int p = 0; p < 4; ++p)
        t[ty + p * 8][tx] = in[(long)(r0 + ty + p * 8) * Cn + c0 + tx];
    __syncthreads();
    #pragma unroll
    for (int p = 0; p < 4; ++p)
        out[(long)(c0 + ty + p * 8) * R + r0 + tx] = __float2bfloat16(t[tx][ty + p * 8]);
}

// ---------------- MFMA GEMM: C[M,N] = A[M,K] * BT[N,K]^T  ---------------------
// Double-buffered K-loop: barrier drains buf[cur] loads, then async-prefetch
// buf[1-cur] while MFMA-computing buf[cur] -> global latency hidden by compute.
// XOR-swizzled LDS chunks (pos = cc ^ (row&7)): conflict-free ds_read_b128.
// EPI: 0 = fp32 store; 1 = bias+relu -> bf16; 2 = bias+residual -> fp32; 3 = bf16 store
template<int K, int EPI>
__global__ __launch_bounds__(256) void gemm_bt(
        const bf16* __restrict__ A, const bf16* __restrict__ BT,
        const float* __restrict__ bias, const float* __restrict__ res,
        float* __restrict__ outF, bf16* __restrict__ outB, int N) {
    __shared__ bf16 As[2][128 * 64];
    __shared__ bf16 Bs[2][128 * 64];

    const int tid = threadIdx.x;
    const int m0 = blockIdx.x * 128;
    const int n0 = blockIdx.y * 128;

    const int ln   = tid & 63;
    const int wid  = tid >> 6;
    const int wm   = (wid & 1) * 64;
    const int wn   = (wid >> 1) * 64;
    const int fr   = ln & 15;
    const int quad = ln >> 4;
    const int sw   = fr & 7;

    f32x4 acc[4][4];
    #pragma unroll
    for (int i = 0; i < 4; ++i)
        #pragma unroll
        for (int j = 0; j < 4; ++j)
            acc[i][j] = (f32x4){0.f, 0.f, 0.f, 0.f};

    const int U = wid * 256 + ln;   // first chunk id of this lane

    const bf16* Abase = A  + (long)m0 * K;
    const bf16* Bbase = BT + (long)n0 * K;

    auto stage = [&](int buf, int k0) {
        #pragma unroll
        for (int it = 0; it < 4; ++it) {
            const int u   = U + (it << 6);
            const int row = u >> 3;
            const int cc  = (u & 7) ^ (row & 7);
            const long gofs = (long)row * K + k0 + cc * 8;
            async_copy16(Abase + gofs, &As[buf][u * 8]);
            async_copy16(Bbase + gofs, &Bs[buf][u * 8]);
        }
    };

    constexpr int NIT = K / 64;
    stage(0, 0);

    for (int ki = 0; ki < NIT; ++ki) {
        const int cur = ki & 1;
        __syncthreads();                       // drains buf[cur] loads; WAR-safe
        if (ki + 1 < NIT) stage(1 - cur, (ki + 1) * 64);   // overlap w/ compute

        #pragma unroll
        for (int kk = 0; kk < 64; kk += 32) {
            const int cb = (kk >> 3) + quad;
            short8 af[4], bfr[4];
            #pragma unroll
            for (int i = 0; i < 4; ++i) {
                const int R = wm + i * 16 + fr;
                af[i] = *(const short8*)(&As[cur][R * 64 + ((cb ^ sw) << 3)]);
            }
            #pragma unroll
            for (int j = 0; j < 4; ++j) {
                const int R = wn + j * 16 + fr;
                bfr[j] = *(const short8*)(&Bs[cur][R * 64 + ((cb ^ sw) << 3)]);
            }
            #pragma unroll
            for (int i = 0; i < 4; ++i)
                #pragma unroll
                for (int j = 0; j < 4; ++j)
                    acc[i][j] = __builtin_amdgcn_mfma_f32_16x16x32_bf16(
                        af[i], bfr[j], acc[i][j], 0, 0, 0);
        }
    }

    #pragma unroll
    for (int i = 0; i < 4; ++i) {
        #pragma unroll
        for (int j = 0; j < 4; ++j) {
            const int col = n0 + wn + j * 16 + fr;
            #pragma unroll
            for (int r = 0; r < 4; ++r) {
                const int row = m0 + wm + i * 16 + quad * 4 + r;
                const long idx = (long)row * N + col;
                float v = acc[i][j][r];
                if (EPI == 0) {
                    outF[idx] = v;
                } else if (EPI == 1) {
                    v = fmaxf(v + bias[col], 0.f);
                    outB[idx] = __float2bfloat16(v);
                } else if (EPI == 2) {
                    outF[idx] = v + bias[col] + res[idx];
                } else {
                    outB[idx] = __float2bfloat16(v);
                }
            }
        }
    }
}

// ---------------- MFMA causal flash attention ---------------------------------
struct alignas(8) bh4s { bf16 a, b, c, d; };

__global__ __launch_bounds__(256, 2) void attn_mfma_kernel(
        const bf16* __restrict__ qkv, bf16* __restrict__ ab) {
    __shared__ bf16 Kt[64][72];
    __shared__ bf16 Vt[64][72];
    __shared__ bf16 Pb[4][16][72];

    const int tid  = threadIdx.x;
    const int bh   = blockIdx.x;
    const int b    = bh / HH, h = bh % HH;
    const int w    = tid >> 6;
    const int ln   = tid & 63;
    const int ln15 = ln & 15;
    const int quad = ln >> 4;

    short8 qf[4][2];
    #pragma unroll
    for (int i = 0; i < 4; ++i) {
        const long tok = (long)b * TT + w * 16 + i * 64 + ln15;
        const bf16* p = qkv + tok * NQKV + h * HSZ + quad * 8;
        qf[i][0] = *(const short8*)p;
        qf[i][1] = *(const short8*)(p + 32);
    }

    f32x4 accO[4][4];
    float mrow[4][4], lrow[4][4];
    #pragma unroll
    for (int i = 0; i < 4; ++i) {
        #pragma unroll
        for (int j = 0; j < 4; ++j) accO[i][j] = (f32x4){0.f, 0.f, 0.f, 0.f};
        #pragma unroll
        for (int r = 0; r < 4; ++r) { mrow[i][r] = -1e30f; lrow[i][r] = 0.f; }
    }

    for (int sidx = 0; sidx < 4; ++sidx) {
        const int s0 = sidx * 64;
        __syncthreads();
        {
            const bf16* kg = qkv + (long)(b * TT + s0) * NQKV + CC + h * HSZ;
            #pragma unroll
            for (int it = 0; it < 2; ++it) {
                const int u = tid + it * 256;
                const int r = u >> 3, c = (u & 7) * 8;
                *(uint4*)&Kt[r][c] = *(const uint4*)(kg + (long)r * NQKV + c);
            }
            const bf16* vg = qkv + (long)(b * TT + s0) * NQKV + 2 * CC + h * HSZ;
            const int s = tid & 63;
            #pragma unroll
            for (int it = 0; it < 4; ++it) {
                const int dq = (tid >> 6) + it * 4;
                const bh4s vv = *(const bh4s*)(vg + (long)s * NQKV + dq * 4);
                Vt[dq * 4 + 0][s] = vv.a;
                Vt[dq * 4 + 1][s] = vv.b;
                Vt[dq * 4 + 2][s] = vv.c;
                Vt[dq * 4 + 3][s] = vv.d;
            }
        }
        __syncthreads();

        for (int i = sidx; i < 4; ++i) {
            const int rb = w * 16 + i * 64;
            f32x4 S[4];
            #pragma unroll
            for (int jt = 0; jt < 4; ++jt) S[jt] = (f32x4){0.f, 0.f, 0.f, 0.f};
            #pragma unroll
            for (int ks = 0; ks < 2; ++ks) {
                #pragma unroll
                for (int jt = 0; jt < 4; ++jt) {
                    const short8 kf = *(const short8*)&Kt[jt * 16 + ln15][ks * 32 + quad * 8];
                    S[jt] = __builtin_amdgcn_mfma_f32_16x16x32_bf16(qf[i][ks], kf, S[jt], 0, 0, 0);
                }
            }
            float rmax[4];
            #pragma unroll
            for (int r = 0; r < 4; ++r) rmax[r] = -1e30f;
            #pragma unroll
            for (int jt = 0; jt < 4; ++jt) {
                #pragma unroll
                for (int r = 0; r < 4; ++r) {
                    float v = S[jt][r] * 0.125f;
                    if (i == sidx) {
                        const int col = s0 + jt * 16 + ln15;
                        const int row = rb + quad * 4 + r;
                        if (col > row) v = -1e30f;
                    }
                    S[jt][r] = v;
                    rmax[r] = fmaxf(rmax[r], v);
                }
            }
            #pragma unroll
            for (int off = 1; off < 16; off <<= 1)
                #pragma unroll
                for (int r = 0; r < 4; ++r)
                    rmax[r] = fmaxf(rmax[r], __shfl_xor(rmax[r], off, 64));

            float alpha[4], rsum[4];
            #pragma unroll
            for (int r = 0; r < 4; ++r) {
                const float mn = fmaxf(mrow[i][r], rmax[r]);
                alpha[r] = __expf(mrow[i][r] - mn);
                mrow[i][r] = mn;
                rsum[r] = 0.f;
            }
            #pragma unroll
            for (int jt = 0; jt < 4; ++jt)
                #pragma unroll
                for (int r = 0; r < 4; ++r) {
                    const float p = __expf(S[jt][r] - mrow[i][r]);
                    S[jt][r] = p;
                    rsum[r] += p;
                }
            #pragma unroll
            for (int off = 1; off < 16; off <<= 1)
                #pragma unroll
                for (int r = 0; r < 4; ++r)
                    rsum[r] += __shfl_xor(rsum[r], off, 64);
            #pragma unroll
            for (int r = 0; r < 4; ++r)
                lrow[i][r] = lrow[i][r] * alpha[r] + rsum[r];
            #pragma unroll
            for (int jt = 0; jt < 4; ++jt)
                #pragma unroll
                for (int r = 0; r < 4; ++r)
                    accO[i][jt][r] *= alpha[r];

            #pragma unroll
            for (int jt = 0; jt < 4; ++jt)
                #pragma unroll
                for (int r = 0; r < 4; ++r)
                    Pb[w][quad * 4 + r][jt * 16 + ln15] = __float2bfloat16(S[jt][r]);
            const short8 pf0 = *(const short8*)&Pb[w][ln15][quad * 8];
            const short8 pf1 = *(const short8*)&Pb[w][ln15][32 + quad * 8];
            #pragma unroll
            for (int jt = 0; jt < 4; ++jt) {
                const short8 vf0 = *(const short8*)&Vt[jt * 16 + ln15][quad * 8];
                const short8 vf1 = *(const short8*)&Vt[jt * 16 + ln15][32 + quad * 8];
                accO[i][jt] = __builtin_amdgcn_mfma_f32_16x16x32_bf16(pf0, vf0, accO[i][jt], 0, 0, 0);
                accO[i][jt] = __builtin_amdgcn_mfma_f32_16x16x32_bf16(pf1, vf1, accO[i][jt], 0, 0, 0);
            }
        }
    }

    #pragma unroll
    for (int i = 0; i < 4; ++i) {
        const int rb = w * 16 + i * 64;
        float inv[4];
        #pragma unroll
        for (int r = 0; r < 4; ++r) inv[r] = 1.0f / lrow[i][r];
        #pragma unroll
        for (int jt = 0; jt < 4; ++jt)
            #pragma unroll
            for (int r = 0; r < 4; ++r)
                Pb[w][quad * 4 + r][jt * 16 + ln15] = __float2bfloat16(accO[i][jt][r] * inv[r]);
        #pragma unroll
        for (int it = 0; it < 2; ++it) {
            const int u = ln + it * 64;
            const int row = u >> 3, ch = (u & 7) * 8;
            const long tok = (long)b * TT + rb + row;
            *(uint4*)(ab + tok * CC + h * HSZ + ch) = *(const uint4*)&Pb[w][row][ch];
        }
    }
}

// ---------------- launcher ----------------------------------------------------
extern "C" void kernel_launch(void* const* d_in, const int* in_sizes, int n_in,
                              void* d_out, int out_size, void* d_ws, size_t ws_size,
                              hipStream_t stream) {
    const float* x   = (const float*)d_in[0];
    const float* Wq  = (const float*)d_in[1];
    const float* Wk  = (const float*)d_in[2];
    const float* Wv  = (const float*)d_in[3];
    const float* Wo  = (const float*)d_in[4];
    const float* bo  = (const float*)d_in[5];
    const float* W1  = (const float*)d_in[6];
    const float* b1  = (const float*)d_in[7];
    const float* W2  = (const float*)d_in[8];
    const float* b2  = (const float*)d_in[9];
    const float* g1  = (const float*)d_in[10];
    const float* be1 = (const float*)d_in[11];
    const float* g2  = (const float*)d_in[12];
    const float* be2 = (const float*)d_in[13];

    float* out = (float*)d_out;
    char*  ws  = (char*)d_ws;

    const size_t qkvBytes = (size_t)NTOK * NQKV * 4;
    const size_t actOff   = (qkvBytes + 255) & ~(size_t)255;
    const size_t actBytes = (size_t)NTOK * CC * 2;
    size_t wOff = (actOff + actBytes + 255) & ~(size_t)255;

    bf16* qkvb = (bf16*)ws;
    bf16* ff1  = (bf16*)ws;
    bf16* actb = (bf16*)(ws + actOff);

    bf16* WcatT = (bf16*)(ws + wOff); wOff += (size_t)NQKV * CC * 2 + 256;
    bf16* WoT   = (bf16*)(ws + ((wOff + 255) & ~(size_t)255)); wOff = ((wOff + 255) & ~(size_t)255) + (size_t)CC * CC * 2;
    bf16* W1T   = (bf16*)(ws + ((wOff + 255) & ~(size_t)255)); wOff = ((wOff + 255) & ~(size_t)255) + (size_t)DFF * CC * 2;
    bf16* W2T   = (bf16*)(ws + ((wOff + 255) & ~(size_t)255));

    pack_qkv_w      <<<NQKV, CC, 0, stream>>>(Wq, Wk, Wv, WcatT);
    transpose_to_bf16<<<dim3(CC / 32,  CC / 32),  256, 0, stream>>>(Wo, WoT, CC,  CC);
    transpose_to_bf16<<<dim3(DFF / 32, CC / 32),  256, 0, stream>>>(W1, W1T, CC,  DFF);
    transpose_to_bf16<<<dim3(CC / 32,  DFF / 32), 256, 0, stream>>>(W2, W2T, DFF, CC);

    ln_bf16_kernel<<<NTOK / RPB, CC, 0, stream>>>(x, g1, be1, actb);
    gemm_bt<CC, 3><<<dim3(NTOK / 128, NQKV / 128), 256, 0, stream>>>(
        actb, WcatT, nullptr, nullptr, nullptr, qkvb, NQKV);
    attn_mfma_kernel<<<BB * HH, 256, 0, stream>>>(qkvb, actb);
    gemm_bt<CC, 2><<<dim3(NTOK / 128, CC / 128), 256, 0, stream>>>(
        actb, WoT, bo, x, out, nullptr, CC);

    ln_bf16_kernel<<<NTOK / RPB, CC, 0, stream>>>(out, g2, be2, actb);
    gemm_bt<CC, 1><<<dim3(NTOK / 128, DFF / 128), 256, 0, stream>>>(
        actb, W1T, b1, nullptr, nullptr, ff1, DFF);
    gemm_bt<DFF, 2><<<dim3(NTOK / 128, CC / 128), 256, 0, stream>>>(
        ff1, W2T, b2, out, out, nullptr, CC);
}

// Round 6
// 513.372 us; speedup vs baseline: 1.1043x; 1.1043x over previous
//
#include <hip/hip_runtime.h>
#include <hip/hip_bf16.h>

#define BB   128
#define TT   256
#define CC   384
#define HH   6
#define HSZ  64
#define DFF  1536
#define EPSV 1e-5f
#define RPB  8
#define NTOK (BB * TT)          // 32768
#define NQKV (3 * CC)           // 1152

typedef __attribute__((ext_vector_type(8))) short  short8;
typedef __attribute__((ext_vector_type(4))) float  f32x4;
typedef __hip_bfloat16 bf16;

// async 16B global -> LDS (lane-contiguous at wave-uniform base)
__device__ __forceinline__ void async_copy16(const bf16* g, bf16* l) {
    __builtin_amdgcn_global_load_lds(
        (const __attribute__((address_space(1))) void*)g,
        (__attribute__((address_space(3))) void*)l, 16, 0, 0);
}

// ---------------- block-wide reduction over 384 threads (6 waves) -------------
__device__ __forceinline__ void block_reduce2(float& a, float& b, float* red) {
    #pragma unroll
    for (int off = 32; off > 0; off >>= 1) {
        a += __shfl_down(a, off, 64);
        b += __shfl_down(b, off, 64);
    }
    const int lane = threadIdx.x & 63;
    const int wid  = threadIdx.x >> 6;
    if (lane == 0) { red[wid * 2] = a; red[wid * 2 + 1] = b; }
    __syncthreads();
    if (threadIdx.x == 0) {
        float sa = 0.f, sb = 0.f;
        #pragma unroll
        for (int w = 0; w < 6; ++w) { sa += red[w * 2]; sb += red[w * 2 + 1]; }
        red[12] = sa; red[13] = sb;
    }
    __syncthreads();
    a = red[12]; b = red[13];
}

// ---------------- LN -> bf16 --------------------------------------------------
__global__ __launch_bounds__(CC) void ln_bf16_kernel(
        const float* __restrict__ x, const float* __restrict__ g,
        const float* __restrict__ be, bf16* __restrict__ y) {
    __shared__ float red[16];
    const int tid = threadIdx.x;
    const long row0 = (long)blockIdx.x * RPB;
    const float gg = g[tid], bb = be[tid];
    for (int r = 0; r < RPB; ++r) {
        float v = x[(row0 + r) * CC + tid];
        float s = v, sq = v * v;
        block_reduce2(s, sq, red);
        float mu  = s  * (1.0f / CC);
        float var = sq * (1.0f / CC) - mu * mu;
        float rs  = rsqrtf(var + EPSV);
        y[(row0 + r) * CC + tid] = __float2bfloat16((v - mu) * rs * gg + bb);
        __syncthreads();
    }
}

// ---------------- unified weight packing (all transposes in ONE launch) -------
// 32x32 transpose tiles. Tile map:
//   [0,432): Wq/Wk/Wv per-head slabs [384][64] -> WcatT rows which*384+h*64..
//   [432,576): Wo [384][384] -> WoT
//   [576,1152): W1 [384][1536] -> W1T
//   [1152,1728): W2 [1536][384] -> W2T
__global__ __launch_bounds__(256) void pack_weights(
        const float* __restrict__ Wq, const float* __restrict__ Wk,
        const float* __restrict__ Wv, const float* __restrict__ Wo,
        const float* __restrict__ W1, const float* __restrict__ W2,
        bf16* __restrict__ WcatT, bf16* __restrict__ WoT,
        bf16* __restrict__ W1T, bf16* __restrict__ W2T) {
    __shared__ float t[32][33];
    const int id = blockIdx.x;
    const float* in; bf16* out; int R, Cn, c0, r0;
    if (id < 432) {
        const int which = id / 144, rem = id % 144, h = rem / 24, tt = rem % 24;
        const float* W = (which == 0) ? Wq : ((which == 1) ? Wk : Wv);
        in = W + (long)h * CC * HSZ;  R = CC; Cn = HSZ;
        c0 = (tt % 2) * 32; r0 = (tt / 2) * 32;
        out = WcatT + ((long)which * CC + h * HSZ) * CC;
    } else if (id < 576) {
        const int i2 = id - 432;
        in = Wo; out = WoT; R = CC; Cn = CC;
        c0 = (i2 % 12) * 32; r0 = (i2 / 12) * 32;
    } else if (id < 1152) {
        const int i3 = id - 576;
        in = W1; out = W1T; R = CC; Cn = DFF;
        c0 = (i3 % 48) * 32; r0 = (i3 / 48) * 32;
    } else {
        const int i4 = id - 1152;
        in = W2; out = W2T; R = DFF; Cn = CC;
        c0 = (i4 % 12) * 32; r0 = (i4 / 12) * 32;
    }
    const int tid = threadIdx.x, tx = tid & 31, ty = tid >> 5;
    #pragma unroll
    for (int p = 0; p < 4; ++p)
        t[ty + p * 8][tx] = in[(long)(r0 + ty + p * 8) * Cn + c0 + tx];
    __syncthreads();
    #pragma unroll
    for (int p = 0; p < 4; ++p)
        out[(long)(c0 + ty + p * 8) * R + r0 + tx] = __float2bfloat16(t[tx][ty + p * 8]);
}

// ---------------- MFMA GEMM 128x128: C[M,N] = A[M,K] * BT[N,K]^T --------------
// Single-buffer async global_load_lds staging, XOR-swizzled chunks (conflict-free).
// EPI: 0 = fp32 store; 1 = bias+relu -> bf16; 2 = bias+residual -> fp32; 3 = bf16 store
template<int K, int EPI>
__global__ __launch_bounds__(256) void gemm_bt(
        const bf16* __restrict__ A, const bf16* __restrict__ BT,
        const float* __restrict__ bias, const float* __restrict__ res,
        float* __restrict__ outF, bf16* __restrict__ outB, int N) {
    __shared__ bf16 As[128 * 64];
    __shared__ bf16 Bs[128 * 64];

    const int tid = threadIdx.x;
    const int m0 = blockIdx.x * 128;
    const int n0 = blockIdx.y * 128;

    const int ln   = tid & 63;
    const int wid  = tid >> 6;
    const int wm   = (wid & 1) * 64;
    const int wn   = (wid >> 1) * 64;
    const int fr   = ln & 15;
    const int quad = ln >> 4;
    const int sw   = fr & 7;

    f32x4 acc[4][4];
    #pragma unroll
    for (int i = 0; i < 4; ++i)
        #pragma unroll
        for (int j = 0; j < 4; ++j)
            acc[i][j] = (f32x4){0.f, 0.f, 0.f, 0.f};

    const int U = wid * 256 + ln;

    for (int k0 = 0; k0 < K; k0 += 64) {
        __syncthreads();
        #pragma unroll
        for (int it = 0; it < 4; ++it) {
            const int u   = U + (it << 6);
            const int row = u >> 3;
            const int cc  = (u & 7) ^ (row & 7);
            const long gofs = (long)row * K + k0 + cc * 8;
            async_copy16(A  + (long)m0 * K + gofs, As + u * 8);
            async_copy16(BT + (long)n0 * K + gofs, Bs + u * 8);
        }
        __syncthreads();
        #pragma unroll
        for (int kk = 0; kk < 64; kk += 32) {
            const int cb = (kk >> 3) + quad;
            short8 af[4], bfr[4];
            #pragma unroll
            for (int i = 0; i < 4; ++i) {
                const int R = wm + i * 16 + fr;
                af[i] = *(const short8*)(As + R * 64 + ((cb ^ sw) << 3));
            }
            #pragma unroll
            for (int j = 0; j < 4; ++j) {
                const int R = wn + j * 16 + fr;
                bfr[j] = *(const short8*)(Bs + R * 64 + ((cb ^ sw) << 3));
            }
            #pragma unroll
            for (int i = 0; i < 4; ++i)
                #pragma unroll
                for (int j = 0; j < 4; ++j)
                    acc[i][j] = __builtin_amdgcn_mfma_f32_16x16x32_bf16(
                        af[i], bfr[j], acc[i][j], 0, 0, 0);
        }
    }

    #pragma unroll
    for (int i = 0; i < 4; ++i) {
        #pragma unroll
        for (int j = 0; j < 4; ++j) {
            const int col = n0 + wn + j * 16 + fr;
            #pragma unroll
            for (int r = 0; r < 4; ++r) {
                const int row = m0 + wm + i * 16 + quad * 4 + r;
                const long idx = (long)row * N + col;
                float v = acc[i][j][r];
                if (EPI == 0) {
                    outF[idx] = v;
                } else if (EPI == 1) {
                    v = fmaxf(v + bias[col], 0.f);
                    outB[idx] = __float2bfloat16(v);
                } else if (EPI == 2) {
                    outF[idx] = v + bias[col] + res[idx];
                } else {
                    outB[idx] = __float2bfloat16(v);
                }
            }
        }
    }
}

// ---------------- MFMA GEMM 64x128 (2 waves): for low-grid GEMMs --------------
// Same structure, M-tile=64 -> 2x grid, 24KB LDS -> 6 blocks/CU.
template<int K, int EPI>
__global__ __launch_bounds__(128) void gemm_bt64(
        const bf16* __restrict__ A, const bf16* __restrict__ BT,
        const float* __restrict__ bias, const float* __restrict__ res,
        float* __restrict__ outF, bf16* __restrict__ outB, int N) {
    __shared__ bf16 As[64 * 64];       // 8 KB
    __shared__ bf16 Bs[128 * 64];      // 16 KB

    const int tid = threadIdx.x;
    const int m0 = blockIdx.x * 64;
    const int n0 = blockIdx.y * 128;

    const int ln   = tid & 63;
    const int wid  = tid >> 6;         // 0,1
    const int wn   = wid * 64;
    const int fr   = ln & 15;
    const int quad = ln >> 4;
    const int sw   = fr & 7;

    f32x4 acc[4][4];
    #pragma unroll
    for (int i = 0; i < 4; ++i)
        #pragma unroll
        for (int j = 0; j < 4; ++j)
            acc[i][j] = (f32x4){0.f, 0.f, 0.f, 0.f};

    for (int k0 = 0; k0 < K; k0 += 64) {
        __syncthreads();
        #pragma unroll
        for (int it = 0; it < 4; ++it) {        // A: 512 chunks over 128 lanes
            const int u   = tid + it * 128;
            const int row = u >> 3;
            const int cc  = (u & 7) ^ (row & 7);
            async_copy16(A + (long)(m0 + row) * K + k0 + cc * 8, As + u * 8);
        }
        #pragma unroll
        for (int it = 0; it < 8; ++it) {        // B: 1024 chunks over 128 lanes
            const int u   = tid + it * 128;
            const int row = u >> 3;
            const int cc  = (u & 7) ^ (row & 7);
            async_copy16(BT + (long)(n0 + row) * K + k0 + cc * 8, Bs + u * 8);
        }
        __syncthreads();
        #pragma unroll
        for (int kk = 0; kk < 64; kk += 32) {
            const int cb = (kk >> 3) + quad;
            short8 af[4], bfr[4];
            #pragma unroll
            for (int i = 0; i < 4; ++i) {
                const int R = i * 16 + fr;
                af[i] = *(const short8*)(As + R * 64 + ((cb ^ sw) << 3));
            }
            #pragma unroll
            for (int j = 0; j < 4; ++j) {
                const int R = wn + j * 16 + fr;
                bfr[j] = *(const short8*)(Bs + R * 64 + ((cb ^ sw) << 3));
            }
            #pragma unroll
            for (int i = 0; i < 4; ++i)
                #pragma unroll
                for (int j = 0; j < 4; ++j)
                    acc[i][j] = __builtin_amdgcn_mfma_f32_16x16x32_bf16(
                        af[i], bfr[j], acc[i][j], 0, 0, 0);
        }
    }

    #pragma unroll
    for (int i = 0; i < 4; ++i) {
        #pragma unroll
        for (int j = 0; j < 4; ++j) {
            const int col = n0 + wn + j * 16 + fr;
            #pragma unroll
            for (int r = 0; r < 4; ++r) {
                const int row = m0 + i * 16 + quad * 4 + r;
                const long idx = (long)row * N + col;
                float v = acc[i][j][r];
                if (EPI == 0) {
                    outF[idx] = v;
                } else if (EPI == 1) {
                    v = fmaxf(v + bias[col], 0.f);
                    outB[idx] = __float2bfloat16(v);
                } else if (EPI == 2) {
                    outF[idx] = v + bias[col] + res[idx];
                } else {
                    outB[idx] = __float2bfloat16(v);
                }
            }
        }
    }
}

// ---------------- MFMA causal flash attention ---------------------------------
struct alignas(8) bh4s { bf16 a, b, c, d; };

__global__ __launch_bounds__(256, 2) void attn_mfma_kernel(
        const bf16* __restrict__ qkv, bf16* __restrict__ ab) {
    __shared__ bf16 Kt[64][72];
    __shared__ bf16 Vt[64][72];
    __shared__ bf16 Pb[4][16][72];

    const int tid  = threadIdx.x;
    const int bh   = blockIdx.x;
    const int b    = bh / HH, h = bh % HH;
    const int w    = tid >> 6;
    const int ln   = tid & 63;
    const int ln15 = ln & 15;
    const int quad = ln >> 4;

    short8 qf[4][2];
    #pragma unroll
    for (int i = 0; i < 4; ++i) {
        const long tok = (long)b * TT + w * 16 + i * 64 + ln15;
        const bf16* p = qkv + tok * NQKV + h * HSZ + quad * 8;
        qf[i][0] = *(const short8*)p;
        qf[i][1] = *(const short8*)(p + 32);
    }

    f32x4 accO[4][4];
    float mrow[4][4], lrow[4][4];
    #pragma unroll
    for (int i = 0; i < 4; ++i) {
        #pragma unroll
        for (int j = 0; j < 4; ++j) accO[i][j] = (f32x4){0.f, 0.f, 0.f, 0.f};
        #pragma unroll
        for (int r = 0; r < 4; ++r) { mrow[i][r] = -1e30f; lrow[i][r] = 0.f; }
    }

    for (int sidx = 0; sidx < 4; ++sidx) {
        const int s0 = sidx * 64;
        __syncthreads();
        {
            const bf16* kg = qkv + (long)(b * TT + s0) * NQKV + CC + h * HSZ;
            #pragma unroll
            for (int it = 0; it < 2; ++it) {
                const int u = tid + it * 256;
                const int r = u >> 3, c = (u & 7) * 8;
                *(uint4*)&Kt[r][c] = *(const uint4*)(kg + (long)r * NQKV + c);
            }
            const bf16* vg = qkv + (long)(b * TT + s0) * NQKV + 2 * CC + h * HSZ;
            const int s = tid & 63;
            #pragma unroll
            for (int it = 0; it < 4; ++it) {
                const int dq = (tid >> 6) + it * 4;
                const bh4s vv = *(const bh4s*)(vg + (long)s * NQKV + dq * 4);
                Vt[dq * 4 + 0][s] = vv.a;
                Vt[dq * 4 + 1][s] = vv.b;
                Vt[dq * 4 + 2][s] = vv.c;
                Vt[dq * 4 + 3][s] = vv.d;
            }
        }
        __syncthreads();

        for (int i = sidx; i < 4; ++i) {
            const int rb = w * 16 + i * 64;
            f32x4 S[4];
            #pragma unroll
            for (int jt = 0; jt < 4; ++jt) S[jt] = (f32x4){0.f, 0.f, 0.f, 0.f};
            #pragma unroll
            for (int ks = 0; ks < 2; ++ks) {
                #pragma unroll
                for (int jt = 0; jt < 4; ++jt) {
                    const short8 kf = *(const short8*)&Kt[jt * 16 + ln15][ks * 32 + quad * 8];
                    S[jt] = __builtin_amdgcn_mfma_f32_16x16x32_bf16(qf[i][ks], kf, S[jt], 0, 0, 0);
                }
            }
            float rmax[4];
            #pragma unroll
            for (int r = 0; r < 4; ++r) rmax[r] = -1e30f;
            #pragma unroll
            for (int jt = 0; jt < 4; ++jt) {
                #pragma unroll
                for (int r = 0; r < 4; ++r) {
                    float v = S[jt][r] * 0.125f;
                    if (i == sidx) {
                        const int col = s0 + jt * 16 + ln15;
                        const int row = rb + quad * 4 + r;
                        if (col > row) v = -1e30f;
                    }
                    S[jt][r] = v;
                    rmax[r] = fmaxf(rmax[r], v);
                }
            }
            #pragma unroll
            for (int off = 1; off < 16; off <<= 1)
                #pragma unroll
                for (int r = 0; r < 4; ++r)
                    rmax[r] = fmaxf(rmax[r], __shfl_xor(rmax[r], off, 64));

            float alpha[4], rsum[4];
            #pragma unroll
            for (int r = 0; r < 4; ++r) {
                const float mn = fmaxf(mrow[i][r], rmax[r]);
                alpha[r] = __expf(mrow[i][r] - mn);
                mrow[i][r] = mn;
                rsum[r] = 0.f;
            }
            #pragma unroll
            for (int jt = 0; jt < 4; ++jt)
                #pragma unroll
                for (int r = 0; r < 4; ++r) {
                    const float p = __expf(S[jt][r] - mrow[i][r]);
                    S[jt][r] = p;
                    rsum[r] += p;
                }
            #pragma unroll
            for (int off = 1; off < 16; off <<= 1)
                #pragma unroll
                for (int r = 0; r < 4; ++r)
                    rsum[r] += __shfl_xor(rsum[r], off, 64);
            #pragma unroll
            for (int r = 0; r < 4; ++r)
                lrow[i][r] = lrow[i][r] * alpha[r] + rsum[r];
            #pragma unroll
            for (int jt = 0; jt < 4; ++jt)
                #pragma unroll
                for (int r = 0; r < 4; ++r)
                    accO[i][jt][r] *= alpha[r];

            #pragma unroll
            for (int jt = 0; jt < 4; ++jt)
                #pragma unroll
                for (int r = 0; r < 4; ++r)
                    Pb[w][quad * 4 + r][jt * 16 + ln15] = __float2bfloat16(S[jt][r]);
            const short8 pf0 = *(const short8*)&Pb[w][ln15][quad * 8];
            const short8 pf1 = *(const short8*)&Pb[w][ln15][32 + quad * 8];
            #pragma unroll
            for (int jt = 0; jt < 4; ++jt) {
                const short8 vf0 = *(const short8*)&Vt[jt * 16 + ln15][quad * 8];
                const short8 vf1 = *(const short8*)&Vt[jt * 16 + ln15][32 + quad * 8];
                accO[i][jt] = __builtin_amdgcn_mfma_f32_16x16x32_bf16(pf0, vf0, accO[i][jt], 0, 0, 0);
                accO[i][jt] = __builtin_amdgcn_mfma_f32_16x16x32_bf16(pf1, vf1, accO[i][jt], 0, 0, 0);
            }
        }
    }

    #pragma unroll
    for (int i = 0; i < 4; ++i) {
        const int rb = w * 16 + i * 64;
        float inv[4];
        #pragma unroll
        for (int r = 0; r < 4; ++r) inv[r] = 1.0f / lrow[i][r];
        #pragma unroll
        for (int jt = 0; jt < 4; ++jt)
            #pragma unroll
            for (int r = 0; r < 4; ++r)
                Pb[w][quad * 4 + r][jt * 16 + ln15] = __float2bfloat16(accO[i][jt][r] * inv[r]);
        #pragma unroll
        for (int it = 0; it < 2; ++it) {
            const int u = ln + it * 64;
            const int row = u >> 3, ch = (u & 7) * 8;
            const long tok = (long)b * TT + rb + row;
            *(uint4*)(ab + tok * CC + h * HSZ + ch) = *(const uint4*)&Pb[w][row][ch];
        }
    }
}

// ---------------- launcher ----------------------------------------------------
extern "C" void kernel_launch(void* const* d_in, const int* in_sizes, int n_in,
                              void* d_out, int out_size, void* d_ws, size_t ws_size,
                              hipStream_t stream) {
    const float* x   = (const float*)d_in[0];
    const float* Wq  = (const float*)d_in[1];
    const float* Wk  = (const float*)d_in[2];
    const float* Wv  = (const float*)d_in[3];
    const float* Wo  = (const float*)d_in[4];
    const float* bo  = (const float*)d_in[5];
    const float* W1  = (const float*)d_in[6];
    const float* b1  = (const float*)d_in[7];
    const float* W2  = (const float*)d_in[8];
    const float* b2  = (const float*)d_in[9];
    const float* g1  = (const float*)d_in[10];
    const float* be1 = (const float*)d_in[11];
    const float* g2  = (const float*)d_in[12];
    const float* be2 = (const float*)d_in[13];

    float* out = (float*)d_out;
    char*  ws  = (char*)d_ws;

    const size_t qkvBytes = (size_t)NTOK * NQKV * 4;
    const size_t actOff   = (qkvBytes + 255) & ~(size_t)255;
    const size_t actBytes = (size_t)NTOK * CC * 2;
    size_t wOff = (actOff + actBytes + 255) & ~(size_t)255;

    bf16* qkvb = (bf16*)ws;
    bf16* ff1  = (bf16*)ws;
    bf16* actb = (bf16*)(ws + actOff);

    bf16* WcatT = (bf16*)(ws + wOff); wOff += (size_t)NQKV * CC * 2 + 256;
    bf16* WoT   = (bf16*)(ws + ((wOff + 255) & ~(size_t)255)); wOff = ((wOff + 255) & ~(size_t)255) + (size_t)CC * CC * 2;
    bf16* W1T   = (bf16*)(ws + ((wOff + 255) & ~(size_t)255)); wOff = ((wOff + 255) & ~(size_t)255) + (size_t)DFF * CC * 2;
    bf16* W2T   = (bf16*)(ws + ((wOff + 255) & ~(size_t)255));

    pack_weights<<<1728, 256, 0, stream>>>(Wq, Wk, Wv, Wo, W1, W2,
                                           WcatT, WoT, W1T, W2T);

    ln_bf16_kernel<<<NTOK / RPB, CC, 0, stream>>>(x, g1, be1, actb);
    gemm_bt<CC, 3><<<dim3(NTOK / 128, NQKV / 128), 256, 0, stream>>>(
        actb, WcatT, nullptr, nullptr, nullptr, qkvb, NQKV);
    attn_mfma_kernel<<<BB * HH, 256, 0, stream>>>(qkvb, actb);
    gemm_bt64<CC, 2><<<dim3(NTOK / 64, CC / 128), 128, 0, stream>>>(
        actb, WoT, bo, x, out, nullptr, CC);

    ln_bf16_kernel<<<NTOK / RPB, CC, 0, stream>>>(out, g2, be2, actb);
    gemm_bt<CC, 1><<<dim3(NTOK / 128, DFF / 128), 256, 0, stream>>>(
        actb, W1T, b1, nullptr, nullptr, ff1, DFF);
    gemm_bt64<DFF, 2><<<dim3(NTOK / 64, CC / 128), 128, 0, stream>>>(
        ff1, W2T, b2, out, out, nullptr, CC);
}